// Round 4
// baseline (1320.967 us; speedup 1.0000x reference)
//
#include <hip/hip_runtime.h>

#define N_ 4
#define C_ 128
#define T_ 512
#define V_ 25
#define H_ 16
#define O_ 128
#define VP_ 32        // padded V rows in v workspace (128B)
#define TV_ (T_*V_)   // 12800

#define TT 16         // t-tile per iteration
#define SP 20         // padded S row stride (16+4): 80B, 16B-aligned, 2-way banks

// Workspace float offsets (same footprint as round 2 — proven to fit)
#define WS_XM    0u
#define WS_Q     262144u
#define WS_K     294912u
#define WS_V     327680u
#define WS_Y     8716288u
#define WS_STATS 15269888u   // 256: sum[128], sumsq[128]
#define WS_SC    15270144u   // 128
#define WS_SH    15270272u   // 128
#define WS_END   15270400u

__device__ __forceinline__ float tanh_fast(float x) {
    float e = __expf(2.f * x);
    return 1.f - 2.f / (e + 1.f);
}

// K0a: xm[n,c,t] = mean over V of x[n,c,t,:]; block 0 also zeroes stats
__global__ void k_xm(const float* __restrict__ x, float* __restrict__ xm,
                     float* __restrict__ stats) {
    int idx = blockIdx.x * 256 + threadIdx.x;        // over N*C*T = 262144
    if (blockIdx.x == 0) stats[threadIdx.x] = 0.f;   // 256 floats
    const float* p = x + (size_t)idx * V_;
    float s = 0.f;
#pragma unroll
    for (int i = 0; i < V_; ++i) s += p[i];
    xm[idx] = s * (1.f / V_);
}

// K0b: q,k[n,h,t] = Wq/Wk @ xm + b
__global__ void k_qk(const float* __restrict__ xm,
                     const float* __restrict__ Wq, const float* __restrict__ bq,
                     const float* __restrict__ Wk, const float* __restrict__ bk,
                     float* __restrict__ q, float* __restrict__ k) {
    int n = blockIdx.x >> 2;             // 4 blocks of 128 t per n
    int t = (blockIdx.x & 3) * 128 + threadIdx.x;
    __shared__ float wq_s[H_ * C_], wk_s[H_ * C_];
    for (int i = threadIdx.x; i < H_ * C_; i += 128) { wq_s[i] = Wq[i]; wk_s[i] = Wk[i]; }
    __syncthreads();
    float qa[H_], ka[H_];
#pragma unroll
    for (int h = 0; h < H_; ++h) { qa[h] = bq[h]; ka[h] = bk[h]; }
    const float* xp = xm + (size_t)n * C_ * T_ + t;
    for (int c = 0; c < C_; ++c) {
        float xv = xp[(size_t)c * T_];
#pragma unroll
        for (int h = 0; h < H_; ++h) {
            qa[h] = fmaf(wq_s[h * C_ + c], xv, qa[h]);
            ka[h] = fmaf(wk_s[h * C_ + c], xv, ka[h]);
        }
    }
#pragma unroll
    for (int h = 0; h < H_; ++h) {
        q[((size_t)n * H_ + h) * T_ + t] = qa[h];
        k[((size_t)n * H_ + h) * T_ + t] = ka[h];
    }
}

// K1: v[n,t,o,vp] = Wv @ x + bv   (layout (n,t,o,VP_), rows padded with zeros)
__global__ void k_v(const float* __restrict__ x, const float* __restrict__ Wv,
                    const float* __restrict__ bv, float* __restrict__ vws) {
    int n = blockIdx.x >> 9;       // 512 t-blocks per n
    int t = blockIdx.x & 511;
    int o = threadIdx.x;           // 128 threads
    __shared__ float xs[C_ * 28];  // padded rows of 28 floats
    for (int i = threadIdx.x; i < C_ * V_; i += 128) {
        int c = i / V_;
        int vi = i - c * V_;
        xs[c * 28 + vi] = x[((size_t)(n * C_ + c) * T_ + t) * V_ + vi];
    }
    __syncthreads();
    float acc[V_];
    float b = bv[o];
#pragma unroll
    for (int i = 0; i < V_; ++i) acc[i] = b;
    for (int c = 0; c < C_; ++c) {
        float w = Wv[o * C_ + c];
        const float4* xr = (const float4*)&xs[c * 28];
#pragma unroll
        for (int u = 0; u < 6; ++u) {
            float4 t4 = xr[u];
            acc[u * 4 + 0] = fmaf(w, t4.x, acc[u * 4 + 0]);
            acc[u * 4 + 1] = fmaf(w, t4.y, acc[u * 4 + 1]);
            acc[u * 4 + 2] = fmaf(w, t4.z, acc[u * 4 + 2]);
            acc[u * 4 + 3] = fmaf(w, t4.w, acc[u * 4 + 3]);
        }
        acc[24] = fmaf(w, xs[c * 28 + 24], acc[24]);
    }
    float* vp = vws + ((size_t)(n * T_ + t) * O_ + o) * VP_;
    float4* vp4 = (float4*)vp;
    float4 w0 = {acc[0], acc[1], acc[2], acc[3]};
    float4 w1 = {acc[4], acc[5], acc[6], acc[7]};
    float4 w2 = {acc[8], acc[9], acc[10], acc[11]};
    float4 w3 = {acc[12], acc[13], acc[14], acc[15]};
    float4 w4 = {acc[16], acc[17], acc[18], acc[19]};
    float4 w5 = {acc[20], acc[21], acc[22], acc[23]};
    float4 w6 = {acc[24], 0.f, 0.f, 0.f};
    float4 w7 = {0.f, 0.f, 0.f, 0.f};
    vp4[0] = w0; vp4[1] = w1; vp4[2] = w2; vp4[3] = w3;
    vp4[4] = w4; vp4[5] = w5; vp4[6] = w6; vp4[7] = w7;
}

// K2: main fused attention kernel
// grid 512 blocks (n:4 × gt:16 × ot:8), 256 threads
// thread = (o_loc = tid>>4, gq = tid&15); owns o = ot*16+o_loc, rows g0=gt*32+gq, g1=g0+16
__global__ __launch_bounds__(256, 4)
void k_main(const float* __restrict__ q, const float* __restrict__ kk,
            const float* __restrict__ vws, const float* __restrict__ Wr,
            const float* __restrict__ br, float* __restrict__ y,
            float* __restrict__ stats) {
    int b = blockIdx.x;
    int n = b >> 7, gt = (b >> 3) & 15, ot = b & 7;
    int tid = threadIdx.x;
    int gq = tid & 15, o_loc = tid >> 4;         // o_loc in 0..15
    int g0 = gt * 32 + gq, g1 = g0 + 16;
    int o = ot * 16 + o_loc;

    __shared__ float S[H_][32][SP];              // 16*32*20*4 = 40960 B

    float wr[H_];
#pragma unroll
    for (int h = 0; h < H_; ++h) wr[h] = Wr[o * H_ + h];
    float br_o = br[o];

    int hA = o_loc;                              // phase-A identity: 16 h values
    float qA0 = q[((size_t)n * H_ + hA) * T_ + g0];
    float qA1 = q[((size_t)n * H_ + hA) * T_ + g1];
    const float* krow = kk + ((size_t)n * H_ + hA) * T_;

    float4 acc0[7], acc1[7];                     // 28 lanes each; 25..27 stay 0
#pragma unroll
    for (int u = 0; u < 7; ++u) {
        acc0[u] = make_float4(0.f, 0.f, 0.f, 0.f);
        acc1[u] = make_float4(0.f, 0.f, 0.f, 0.f);
    }

    const float* vbase = vws + (size_t)n * T_ * O_ * VP_ + (size_t)o * VP_;

    for (int tt = 0; tt < T_ / TT; ++tt) {
        int t0 = tt * TT;
        __syncthreads();   // S consumed by previous phase B
        // Phase A: S[hA][g0][*], S[hA][g1][*] = tanh(q - k[t0..t0+15])
        {
            const float4* kp = (const float4*)(krow + t0);
#pragma unroll
            for (int j = 0; j < 4; ++j) {
                float4 kv = kp[j];
                float4 s0, s1;
                s0.x = tanh_fast(qA0 - kv.x);  s1.x = tanh_fast(qA1 - kv.x);
                s0.y = tanh_fast(qA0 - kv.y);  s1.y = tanh_fast(qA1 - kv.y);
                s0.z = tanh_fast(qA0 - kv.z);  s1.z = tanh_fast(qA1 - kv.z);
                s0.w = tanh_fast(qA0 - kv.w);  s1.w = tanh_fast(qA1 - kv.w);
                *(float4*)&S[hA][gq][4 * j]      = s0;
                *(float4*)&S[hA][gq + 16][4 * j] = s1;
            }
        }
        __syncthreads();
        // Phase B: A = Wr·S + br for both g rows, then acc += A * v
#pragma unroll 1
        for (int j4 = 0; j4 < 4; ++j4) {
            float a0[4] = {br_o, br_o, br_o, br_o};
            float a1[4] = {br_o, br_o, br_o, br_o};
#pragma unroll
            for (int h = 0; h < H_; ++h) {
                float w = wr[h];
                float4 sa = *(const float4*)&S[h][gq][4 * j4];
                float4 sb = *(const float4*)&S[h][gq + 16][4 * j4];
                a0[0] = fmaf(w, sa.x, a0[0]);
                a0[1] = fmaf(w, sa.y, a0[1]);
                a0[2] = fmaf(w, sa.z, a0[2]);
                a0[3] = fmaf(w, sa.w, a0[3]);
                a1[0] = fmaf(w, sb.x, a1[0]);
                a1[1] = fmaf(w, sb.y, a1[1]);
                a1[2] = fmaf(w, sb.z, a1[2]);
                a1[3] = fmaf(w, sb.w, a1[3]);
            }
#pragma unroll
            for (int r = 0; r < 4; ++r) {
                const float4* vp4 = (const float4*)(vbase + (size_t)(t0 + j4 * 4 + r) * O_ * VP_);
                float A0 = a0[r], A1 = a1[r];
#pragma unroll
                for (int u = 0; u < 7; ++u) {
                    float4 vv = vp4[u];
                    acc0[u].x = fmaf(A0, vv.x, acc0[u].x);
                    acc0[u].y = fmaf(A0, vv.y, acc0[u].y);
                    acc0[u].z = fmaf(A0, vv.z, acc0[u].z);
                    acc0[u].w = fmaf(A0, vv.w, acc0[u].w);
                    acc1[u].x = fmaf(A1, vv.x, acc1[u].x);
                    acc1[u].y = fmaf(A1, vv.y, acc1[u].y);
                    acc1[u].z = fmaf(A1, vv.z, acc1[u].z);
                    acc1[u].w = fmaf(A1, vv.w, acc1[u].w);
                }
            }
        }
    }

    // write y (pre-BN), layout (n,o,g,v) == x layout
    const float* a0f = (const float*)acc0;
    const float* a1f = (const float*)acc1;
    float* yp0 = y + (((size_t)(n * O_ + o)) * T_ + g0) * V_;
    float* yp1 = y + (((size_t)(n * O_ + o)) * T_ + g1) * V_;
#pragma unroll
    for (int i = 0; i < V_; ++i) { yp0[i] = a0f[i]; yp1[i] = a1f[i]; }

    // BN partial stats: reduce over the 16 gq-lanes sharing o (pads are exact zeros)
    float s1 = 0.f, s2 = 0.f;
#pragma unroll
    for (int i = 0; i < V_; ++i) {
        s1 += a0f[i] + a1f[i];
        s2 = fmaf(a0f[i], a0f[i], s2);
        s2 = fmaf(a1f[i], a1f[i], s2);
    }
#pragma unroll
    for (int m = 8; m > 0; m >>= 1) {
        s1 += __shfl_xor(s1, m);
        s2 += __shfl_xor(s2, m);
    }
    if (gq == 0) {
        atomicAdd(stats + o, s1);
        atomicAdd(stats + O_ + o, s2);
    }
}

// K3: finalize BN stats -> scale/shift
__global__ void k_stats(const float* __restrict__ stats,
                        const float* __restrict__ gamma, const float* __restrict__ beta,
                        float* __restrict__ sc, float* __restrict__ sh) {
    int o = threadIdx.x;   // 128
    const float invM = 1.f / (float)(N_ * T_ * V_);
    float mean = stats[o] * invM;
    float var = stats[O_ + o] * invM - mean * mean;
    float rstd = rsqrtf(var + 1e-5f);
    float s = gamma[o] * rstd;
    sc[o] = s;
    sh[o] = beta[o] - mean * s;
}

// K4: out = relu(y*sc[o] + sh[o] + x), float4 over N*O*T*V
__global__ void k_bnout(const float* __restrict__ y, const float* __restrict__ x,
                        const float* __restrict__ sc, const float* __restrict__ sh,
                        float* __restrict__ out) {
    int q4 = blockIdx.x * 256 + threadIdx.x;   // 1638400 quads
    int row = q4 / (TV_ / 4);                  // n*O_+o  (TV_/4 = 3200)
    int o = row & (O_ - 1);
    float4 yv = ((const float4*)y)[q4];
    float4 xv = ((const float4*)x)[q4];
    float s = sc[o], b = sh[o];
    float4 r;
    r.x = fmaxf(fmaf(yv.x, s, b) + xv.x, 0.f);
    r.y = fmaxf(fmaf(yv.y, s, b) + xv.y, 0.f);
    r.z = fmaxf(fmaf(yv.z, s, b) + xv.z, 0.f);
    r.w = fmaxf(fmaf(yv.w, s, b) + xv.w, 0.f);
    ((float4*)out)[q4] = r;
}

extern "C" void kernel_launch(void* const* d_in, const int* in_sizes, int n_in,
                              void* d_out, int out_size, void* d_ws, size_t ws_size,
                              hipStream_t stream) {
    const float* x     = (const float*)d_in[0];
    const float* Wq    = (const float*)d_in[1];
    const float* bq    = (const float*)d_in[2];
    const float* Wk    = (const float*)d_in[3];
    const float* bk    = (const float*)d_in[4];
    const float* Wv    = (const float*)d_in[5];
    const float* bv    = (const float*)d_in[6];
    const float* Wr    = (const float*)d_in[7];
    const float* br    = (const float*)d_in[8];
    const float* gamma = (const float*)d_in[9];
    const float* beta  = (const float*)d_in[10];
    float* out = (float*)d_out;
    float* ws  = (float*)d_ws;

    if (ws_size < (size_t)WS_END * sizeof(float)) return;  // insufficient scratch

    float* xm    = ws + WS_XM;
    float* q     = ws + WS_Q;
    float* k     = ws + WS_K;
    float* vws   = ws + WS_V;
    float* y     = ws + WS_Y;
    float* stats = ws + WS_STATS;
    float* sc    = ws + WS_SC;
    float* sh    = ws + WS_SH;

    k_xm<<<1024, 256, 0, stream>>>(x, xm, stats);
    k_qk<<<16, 128, 0, stream>>>(xm, Wq, bq, Wk, bk, q, k);
    k_v<<<2048, 128, 0, stream>>>(x, Wv, bv, vws);
    k_main<<<512, 256, 0, stream>>>(q, k, vws, Wr, br, y, stats);
    k_stats<<<1, 128, 0, stream>>>(stats, gamma, beta, sc, sh);
    k_bnout<<<6400, 256, 0, stream>>>(y, x, sc, sh, out);
}

// Round 5
// 486.659 us; speedup vs baseline: 2.7144x; 2.7144x over previous
//
#include <hip/hip_runtime.h>

#define N_ 4
#define C_ 128
#define T_ 512
#define V_ 25
#define H_ 16
#define O_ 128
#define VP_ 32        // padded V rows in v workspace (128B)
#define TV_ (T_*V_)   // 12800

#define TT 16         // t-tile per iteration
#define SP 20         // padded S row stride (16+4): 80B, 16B-aligned

// Workspace float offsets
#define WS_XM    0u
#define WS_Q     262144u
#define WS_K     294912u
#define WS_V     327680u
#define WS_Y     8716288u
#define WS_STATS 15269888u   // 256: sum[128], sumsq[128]
#define WS_SC    15270144u   // 128
#define WS_SH    15270272u   // 128
#define WS_END   15270400u

__device__ __forceinline__ float tanh_fast(float x) {
    float e = __expf(2.f * x);
    return 1.f - 2.f / (e + 1.f);
}

// K0a: xm[n,c,t] = mean over V of x[n,c,t,:]; block 0 also zeroes stats
__global__ void k_xm(const float* __restrict__ x, float* __restrict__ xm,
                     float* __restrict__ stats) {
    int idx = blockIdx.x * 256 + threadIdx.x;        // over N*C*T = 262144
    if (blockIdx.x == 0) stats[threadIdx.x] = 0.f;   // 256 floats
    const float* p = x + (size_t)idx * V_;
    float s = 0.f;
#pragma unroll
    for (int i = 0; i < V_; ++i) s += p[i];
    xm[idx] = s * (1.f / V_);
}

// K0b: q,k[n,h,t] = Wq/Wk @ xm + b
__global__ void k_qk(const float* __restrict__ xm,
                     const float* __restrict__ Wq, const float* __restrict__ bq,
                     const float* __restrict__ Wk, const float* __restrict__ bk,
                     float* __restrict__ q, float* __restrict__ k) {
    int n = blockIdx.x >> 2;             // 4 blocks of 128 t per n
    int t = (blockIdx.x & 3) * 128 + threadIdx.x;
    __shared__ float wq_s[H_ * C_], wk_s[H_ * C_];
    for (int i = threadIdx.x; i < H_ * C_; i += 128) { wq_s[i] = Wq[i]; wk_s[i] = Wk[i]; }
    __syncthreads();
    float qa[H_], ka[H_];
#pragma unroll
    for (int h = 0; h < H_; ++h) { qa[h] = bq[h]; ka[h] = bk[h]; }
    const float* xp = xm + (size_t)n * C_ * T_ + t;
    for (int c = 0; c < C_; ++c) {
        float xv = xp[(size_t)c * T_];
#pragma unroll
        for (int h = 0; h < H_; ++h) {
            qa[h] = fmaf(wq_s[h * C_ + c], xv, qa[h]);
            ka[h] = fmaf(wk_s[h * C_ + c], xv, ka[h]);
        }
    }
#pragma unroll
    for (int h = 0; h < H_; ++h) {
        q[((size_t)n * H_ + h) * T_ + t] = qa[h];
        k[((size_t)n * H_ + h) * T_ + t] = ka[h];
    }
}

// K1: v[n,t,o,vp] = Wv @ x + bv   (layout (n,t,o,VP_), rows padded with zeros)
__global__ void k_v(const float* __restrict__ x, const float* __restrict__ Wv,
                    const float* __restrict__ bv, float* __restrict__ vws) {
    int n = blockIdx.x >> 9;       // 512 t-blocks per n
    int t = blockIdx.x & 511;
    int o = threadIdx.x;           // 128 threads
    __shared__ float xs[C_ * 28];  // padded rows of 28 floats
    for (int i = threadIdx.x; i < C_ * V_; i += 128) {
        int c = i / V_;
        int vi = i - c * V_;
        xs[c * 28 + vi] = x[((size_t)(n * C_ + c) * T_ + t) * V_ + vi];
    }
    __syncthreads();
    float acc[V_];
    float b = bv[o];
#pragma unroll
    for (int i = 0; i < V_; ++i) acc[i] = b;
    for (int c = 0; c < C_; ++c) {
        float w = Wv[o * C_ + c];
        const float4* xr = (const float4*)&xs[c * 28];
#pragma unroll
        for (int u = 0; u < 6; ++u) {
            float4 t4 = xr[u];
            acc[u * 4 + 0] = fmaf(w, t4.x, acc[u * 4 + 0]);
            acc[u * 4 + 1] = fmaf(w, t4.y, acc[u * 4 + 1]);
            acc[u * 4 + 2] = fmaf(w, t4.z, acc[u * 4 + 2]);
            acc[u * 4 + 3] = fmaf(w, t4.w, acc[u * 4 + 3]);
        }
        acc[24] = fmaf(w, xs[c * 28 + 24], acc[24]);
    }
    float* vp = vws + ((size_t)(n * T_ + t) * O_ + o) * VP_;
    float4* vp4 = (float4*)vp;
    float4 w0 = {acc[0], acc[1], acc[2], acc[3]};
    float4 w1 = {acc[4], acc[5], acc[6], acc[7]};
    float4 w2 = {acc[8], acc[9], acc[10], acc[11]};
    float4 w3 = {acc[12], acc[13], acc[14], acc[15]};
    float4 w4 = {acc[16], acc[17], acc[18], acc[19]};
    float4 w5 = {acc[20], acc[21], acc[22], acc[23]};
    float4 w6 = {acc[24], 0.f, 0.f, 0.f};
    float4 w7 = {0.f, 0.f, 0.f, 0.f};
    vp4[0] = w0; vp4[1] = w1; vp4[2] = w2; vp4[3] = w3;
    vp4[4] = w4; vp4[5] = w5; vp4[6] = w6; vp4[7] = w7;
}

// K2: main fused attention kernel
// grid 512 blocks (n:4 × gt:16 × ot:8), 256 threads
// thread = (o_loc = tid>>4, gq = tid&15); owns o = ot*16+o_loc, rows g0=gt*32+gq, g1=g0+16
// Single-arg launch_bounds: no waves-per-EU constraint -> allocator free to use ~120 VGPRs.
__global__ __launch_bounds__(256)
void k_main(const float* __restrict__ q, const float* __restrict__ kk,
            const float* __restrict__ vws, const float* __restrict__ Wr,
            const float* __restrict__ br, float* __restrict__ y,
            float* __restrict__ stats) {
    int b = blockIdx.x;
    int n = b >> 7, gt = (b >> 3) & 15, ot = b & 7;
    int tid = threadIdx.x;
    int gq = tid & 15, o_loc = tid >> 4;         // o_loc in 0..15
    int g0 = gt * 32 + gq, g1 = g0 + 16;
    int o = ot * 16 + o_loc;

    __shared__ float S[H_][32][SP];              // 16*32*20*4 = 40960 B

    float wr[H_];
#pragma unroll
    for (int h = 0; h < H_; ++h) wr[h] = Wr[o * H_ + h];
    float br_o = br[o];

    int hA = o_loc;                              // phase-A identity: 16 h values
    float qA0 = q[((size_t)n * H_ + hA) * T_ + g0];
    float qA1 = q[((size_t)n * H_ + hA) * T_ + g1];
    const float* krow = kk + ((size_t)n * H_ + hA) * T_;

    float4 acc0[7], acc1[7];                     // 28 lanes each; 25..27 stay 0
#pragma unroll
    for (int u = 0; u < 7; ++u) {
        acc0[u] = make_float4(0.f, 0.f, 0.f, 0.f);
        acc1[u] = make_float4(0.f, 0.f, 0.f, 0.f);
    }

    const float* vbase = vws + (size_t)n * T_ * O_ * VP_ + (size_t)o * VP_;

    for (int tt = 0; tt < T_ / TT; ++tt) {
        int t0 = tt * TT;
        __syncthreads();   // S consumed by previous phase B
        // Phase A: S[hA][g0][*], S[hA][g1][*] = tanh(q - k[t0..t0+15])
        {
            const float4* kp = (const float4*)(krow + t0);
#pragma unroll
            for (int j = 0; j < 4; ++j) {
                float4 kv = kp[j];
                float4 s0, s1;
                s0.x = tanh_fast(qA0 - kv.x);  s1.x = tanh_fast(qA1 - kv.x);
                s0.y = tanh_fast(qA0 - kv.y);  s1.y = tanh_fast(qA1 - kv.y);
                s0.z = tanh_fast(qA0 - kv.z);  s1.z = tanh_fast(qA1 - kv.z);
                s0.w = tanh_fast(qA0 - kv.w);  s1.w = tanh_fast(qA1 - kv.w);
                *(float4*)&S[hA][gq][4 * j]      = s0;
                *(float4*)&S[hA][gq + 16][4 * j] = s1;
            }
        }
        __syncthreads();
        // Phase B: A = Wr·S + br for both g rows, then acc += A * v
#pragma unroll 1
        for (int j4 = 0; j4 < 4; ++j4) {
            float a0[4] = {br_o, br_o, br_o, br_o};
            float a1[4] = {br_o, br_o, br_o, br_o};
#pragma unroll
            for (int h = 0; h < H_; ++h) {
                float w = wr[h];
                float4 sa = *(const float4*)&S[h][gq][4 * j4];
                float4 sb = *(const float4*)&S[h][gq + 16][4 * j4];
                a0[0] = fmaf(w, sa.x, a0[0]);
                a0[1] = fmaf(w, sa.y, a0[1]);
                a0[2] = fmaf(w, sa.z, a0[2]);
                a0[3] = fmaf(w, sa.w, a0[3]);
                a1[0] = fmaf(w, sb.x, a1[0]);
                a1[1] = fmaf(w, sb.y, a1[1]);
                a1[2] = fmaf(w, sb.z, a1[2]);
                a1[3] = fmaf(w, sb.w, a1[3]);
            }
#pragma unroll
            for (int r = 0; r < 4; ++r) {
                const float4* vp4 = (const float4*)(vbase + (size_t)(t0 + j4 * 4 + r) * O_ * VP_);
                float A0 = a0[r], A1 = a1[r];
#pragma unroll
                for (int u = 0; u < 7; ++u) {
                    float4 vv = vp4[u];
                    acc0[u].x = fmaf(A0, vv.x, acc0[u].x);
                    acc0[u].y = fmaf(A0, vv.y, acc0[u].y);
                    acc0[u].z = fmaf(A0, vv.z, acc0[u].z);
                    acc0[u].w = fmaf(A0, vv.w, acc0[u].w);
                    acc1[u].x = fmaf(A1, vv.x, acc1[u].x);
                    acc1[u].y = fmaf(A1, vv.y, acc1[u].y);
                    acc1[u].z = fmaf(A1, vv.z, acc1[u].z);
                    acc1[u].w = fmaf(A1, vv.w, acc1[u].w);
                }
            }
        }
    }

    // write y (pre-BN), layout (n,o,g,v) == x layout — component-wise, no
    // pointer-casting of register arrays (avoid SROA failure -> scratch).
    float* yp0 = y + (((size_t)(n * O_ + o)) * T_ + g0) * V_;
    float* yp1 = y + (((size_t)(n * O_ + o)) * T_ + g1) * V_;
#pragma unroll
    for (int u = 0; u < 6; ++u) {
        yp0[4 * u + 0] = acc0[u].x;  yp0[4 * u + 1] = acc0[u].y;
        yp0[4 * u + 2] = acc0[u].z;  yp0[4 * u + 3] = acc0[u].w;
        yp1[4 * u + 0] = acc1[u].x;  yp1[4 * u + 1] = acc1[u].y;
        yp1[4 * u + 2] = acc1[u].z;  yp1[4 * u + 3] = acc1[u].w;
    }
    yp0[24] = acc0[6].x;
    yp1[24] = acc1[6].x;

    // BN partial stats (pad lanes are exact zeros -> harmless in both sums)
    float s1 = 0.f, s2 = 0.f;
#pragma unroll
    for (int u = 0; u < 7; ++u) {
        s1 += acc0[u].x + acc0[u].y + acc0[u].z + acc0[u].w;
        s1 += acc1[u].x + acc1[u].y + acc1[u].z + acc1[u].w;
        s2 = fmaf(acc0[u].x, acc0[u].x, s2);  s2 = fmaf(acc0[u].y, acc0[u].y, s2);
        s2 = fmaf(acc0[u].z, acc0[u].z, s2);  s2 = fmaf(acc0[u].w, acc0[u].w, s2);
        s2 = fmaf(acc1[u].x, acc1[u].x, s2);  s2 = fmaf(acc1[u].y, acc1[u].y, s2);
        s2 = fmaf(acc1[u].z, acc1[u].z, s2);  s2 = fmaf(acc1[u].w, acc1[u].w, s2);
    }
#pragma unroll
    for (int m = 8; m > 0; m >>= 1) {
        s1 += __shfl_xor(s1, m);
        s2 += __shfl_xor(s2, m);
    }
    if (gq == 0) {
        atomicAdd(stats + o, s1);
        atomicAdd(stats + O_ + o, s2);
    }
}

// K3: finalize BN stats -> scale/shift
__global__ void k_stats(const float* __restrict__ stats,
                        const float* __restrict__ gamma, const float* __restrict__ beta,
                        float* __restrict__ sc, float* __restrict__ sh) {
    int o = threadIdx.x;   // 128
    const float invM = 1.f / (float)(N_ * T_ * V_);
    float mean = stats[o] * invM;
    float var = stats[O_ + o] * invM - mean * mean;
    float rstd = rsqrtf(var + 1e-5f);
    float s = gamma[o] * rstd;
    sc[o] = s;
    sh[o] = beta[o] - mean * s;
}

// K4: out = relu(y*sc[o] + sh[o] + x), float4 over N*O*T*V
__global__ void k_bnout(const float* __restrict__ y, const float* __restrict__ x,
                        const float* __restrict__ sc, const float* __restrict__ sh,
                        float* __restrict__ out) {
    int q4 = blockIdx.x * 256 + threadIdx.x;   // 1638400 quads
    int row = q4 / (TV_ / 4);                  // n*O_+o  (TV_/4 = 3200)
    int o = row & (O_ - 1);
    float4 yv = ((const float4*)y)[q4];
    float4 xv = ((const float4*)x)[q4];
    float s = sc[o], b = sh[o];
    float4 r;
    r.x = fmaxf(fmaf(yv.x, s, b) + xv.x, 0.f);
    r.y = fmaxf(fmaf(yv.y, s, b) + xv.y, 0.f);
    r.z = fmaxf(fmaf(yv.z, s, b) + xv.z, 0.f);
    r.w = fmaxf(fmaf(yv.w, s, b) + xv.w, 0.f);
    ((float4*)out)[q4] = r;
}

extern "C" void kernel_launch(void* const* d_in, const int* in_sizes, int n_in,
                              void* d_out, int out_size, void* d_ws, size_t ws_size,
                              hipStream_t stream) {
    const float* x     = (const float*)d_in[0];
    const float* Wq    = (const float*)d_in[1];
    const float* bq    = (const float*)d_in[2];
    const float* Wk    = (const float*)d_in[3];
    const float* bk    = (const float*)d_in[4];
    const float* Wv    = (const float*)d_in[5];
    const float* bv    = (const float*)d_in[6];
    const float* Wr    = (const float*)d_in[7];
    const float* br    = (const float*)d_in[8];
    const float* gamma = (const float*)d_in[9];
    const float* beta  = (const float*)d_in[10];
    float* out = (float*)d_out;
    float* ws  = (float*)d_ws;

    if (ws_size < (size_t)WS_END * sizeof(float)) return;  // insufficient scratch

    float* xm    = ws + WS_XM;
    float* q     = ws + WS_Q;
    float* k     = ws + WS_K;
    float* vws   = ws + WS_V;
    float* y     = ws + WS_Y;
    float* stats = ws + WS_STATS;
    float* sc    = ws + WS_SC;
    float* sh    = ws + WS_SH;

    k_xm<<<1024, 256, 0, stream>>>(x, xm, stats);
    k_qk<<<16, 128, 0, stream>>>(xm, Wq, bq, Wk, bk, q, k);
    k_v<<<2048, 128, 0, stream>>>(x, Wv, bv, vws);
    k_main<<<512, 256, 0, stream>>>(q, k, vws, Wr, br, y, stats);
    k_stats<<<1, 128, 0, stream>>>(stats, gamma, beta, sc, sh);
    k_bnout<<<6400, 256, 0, stream>>>(y, x, sc, sh, out);
}